// Round 16
// baseline (139.366 us; speedup 1.0000x reference)
//
#include <hip/hip_runtime.h>
#include <math.h>

#define NB 32
#define ND 128
#define NC 1024
#define NQ 256
#define NEGV (-1e30f)

typedef __attribute__((ext_vector_type(8))) __bf16 bf16x8;
typedef __attribute__((ext_vector_type(4))) float f32x4;
typedef __attribute__((ext_vector_type(8))) unsigned short u16x8;
typedef __attribute__((ext_vector_type(4))) unsigned short u16x4;

__device__ inline unsigned short f2bf(float f) {
  unsigned u = __builtin_bit_cast(unsigned, f);
  u += 0x7FFFu + ((u >> 16) & 1u);
  return (unsigned short)(u >> 16);
}
__device__ inline float bf2f(unsigned short u) {
  return __builtin_bit_cast(float, (unsigned)u << 16);
}

// ---------------- k_prep: fused {cprep | qprep | pwcvt} dispatcher (1-D grid 672)
__global__ __launch_bounds__(256) void k_prep(const float* __restrict__ C, const float* __restrict__ Q,
                                              const float* __restrict__ pwW, const float* __restrict__ W0,
                                              unsigned short* __restrict__ cw3T, unsigned short* __restrict__ cSwz,
                                              float* __restrict__ cb,
                                              unsigned short* __restrict__ qSwz, unsigned short* __restrict__ qT,
                                              float* __restrict__ qb,
                                              unsigned short* __restrict__ pwB16) {
  __shared__ unsigned short T2[128 * 66];
  __shared__ float wA[128], wB[128];
  __shared__ float redP[4][64];
  int bid = blockIdx.x, t = threadIdx.x;
  if (bid < 512) {
    // ---- cprep: C pass -> cw3T, cSwz, cb
    int b = bid >> 4, tile = bid & 15, i0 = tile * 64;
    if (t < 128) { wA[t] = W0[t]; wB[t] = W0[2 * ND + t]; }
    int k = t >> 1, half = t & 1;
    const float* src = C + ((size_t)b * ND + k) * NC + i0 + half * 32;
    unsigned short* cdst = cSwz + ((size_t)b * ND + k) * NC + tile * 64;
    #pragma unroll
    for (int q = 0; q < 4; ++q) {
      float4 v0 = ((const float4*)src)[q * 2];
      float4 v1 = ((const float4*)src)[q * 2 + 1];
      u16x8 o;
      o[0] = f2bf(v0.x); o[1] = f2bf(v0.y); o[2] = f2bf(v0.z); o[3] = f2bf(v0.w);
      o[4] = f2bf(v1.x); o[5] = f2bf(v1.y); o[6] = f2bf(v1.z); o[7] = f2bf(v1.w);
      *(u16x8*)&T2[k * 66 + half * 32 + q * 8] = o;
      int g = half * 4 + q;
      *(u16x8*)&cdst[(g ^ (k & 7)) * 8] = o;
    }
    __syncthreads();
    {
      int ii = t & 63, kq = t >> 6;
      float s = 0.f;
      #pragma unroll 8
      for (int kk = 0; kk < 32; ++kk) {
        int dd = kq * 32 + kk;
        s += bf2f(T2[dd * 66 + ii]) * wA[dd];
      }
      redP[kq][ii] = s;
    }
    __syncthreads();
    if (t < 64)
      cb[b * NC + i0 + t] = redP[0][t] + redP[1][t] + redP[2][t] + redP[3][t];
    {
      int ii = t >> 2, p = t & 3;
      unsigned short* dst = cw3T + ((size_t)b * NC + i0 + ii) * ND;
      #pragma unroll
      for (int q = 0; q < 4; ++q) {
        int g = p * 4 + q;
        u16x8 o;
        #pragma unroll
        for (int e = 0; e < 8; ++e)
          o[e] = f2bf(bf2f(T2[(g * 8 + e) * 66 + ii]) * wB[g * 8 + e]);
        int sg = (g & 8) | ((g & 7) ^ (ii & 7));
        *(u16x8*)&dst[sg * 8] = o;
      }
    }
  } else if (bid < 640) {
    // ---- qprep: Q pass -> qSwz, qT, qb
    int r = bid - 512, b = r >> 2, jc = r & 3, j0 = jc * 64;
    if (t < 128) wA[t] = W0[ND + t];
    int d = t >> 1, half = t & 1;
    const float* src = Q + ((size_t)b * ND + d) * NQ + j0 + half * 32;
    unsigned short* qdst = qSwz + ((size_t)b * ND + d) * NQ + jc * 64;
    #pragma unroll
    for (int q = 0; q < 4; ++q) {
      float4 v0 = ((const float4*)src)[q * 2];
      float4 v1 = ((const float4*)src)[q * 2 + 1];
      u16x8 o;
      o[0] = f2bf(v0.x); o[1] = f2bf(v0.y); o[2] = f2bf(v0.z); o[3] = f2bf(v0.w);
      o[4] = f2bf(v1.x); o[5] = f2bf(v1.y); o[6] = f2bf(v1.z); o[7] = f2bf(v1.w);
      *(u16x8*)&T2[d * 66 + half * 32 + q * 8] = o;
      int g = half * 4 + q;
      *(u16x8*)&qdst[(g ^ (d & 7)) * 8] = o;
    }
    __syncthreads();
    {
      int jj = t & 63, dq = t >> 6;
      float s = 0.f;
      #pragma unroll 8
      for (int k = 0; k < 32; ++k) {
        int dd = dq * 32 + k;
        s += bf2f(T2[dd * 66 + jj]) * wA[dd];
      }
      redP[dq][jj] = s;
    }
    __syncthreads();
    if (t < 64)
      qb[b * NQ + j0 + t] = redP[0][t] + redP[1][t] + redP[2][t] + redP[3][t];
    {
      int jj = t >> 2, p = t & 3;
      unsigned short* dst = qT + ((size_t)b * NQ + j0 + jj) * ND;
      #pragma unroll
      for (int q = 0; q < 4; ++q) {
        int g = p * 4 + q;
        u16x8 o;
        #pragma unroll
        for (int e = 0; e < 8; ++e) o[e] = T2[(g * 8 + e) * 66 + jj];
        int sg = (g & 8) | ((g & 7) ^ (jj & 7));
        *(u16x8*)&dst[sg * 8] = o;
      }
    }
  } else {
    // ---- pwcvt: pwW f32 -> bf16
    int idx = (bid - 640) * 256 + t;   // 0..8191
    const float4* src = (const float4*)pwW;
    float4 v0 = src[idx * 2], v1 = src[idx * 2 + 1];
    u16x8 o;
    o[0] = f2bf(v0.x); o[1] = f2bf(v0.y); o[2] = f2bf(v0.z); o[3] = f2bf(v0.w);
    o[4] = f2bf(v1.x); o[5] = f2bf(v1.y); o[6] = f2bf(v1.z); o[7] = f2bf(v1.w);
    ((u16x8*)pwB16)[idx] = o;
  }
}

// ---------------- k_stats: MFMA S + full row stats + col partials. Tile 64i x 256j.
__global__ __launch_bounds__(256) void k_stats(const unsigned short* __restrict__ cw3T,
                                               const unsigned short* __restrict__ qT,
                                               const float* __restrict__ cb, const float* __restrict__ qb,
                                               const float* __restrict__ q_mask, const float* __restrict__ c_mask,
                                               float* __restrict__ rowmax, float* __restrict__ rowsum,
                                               float* __restrict__ colPm, float* __restrict__ colPs) {
  __shared__ float rmP[64][4], rsP[64][4];
  __shared__ float cbL[64], cmL[64], qbL[256], qmL[256];
  int b = blockIdx.y, i0 = blockIdx.x * 64;
  int t = threadIdx.x, w = t >> 6, l = t & 63, h = l >> 4, lr = l & 15;
  int wj = w * 64;
  if (t < 64) { cbL[t] = cb[b * NC + i0 + t]; cmL[t] = c_mask[b * NC + i0 + t]; }
  qbL[t] = qb[b * NQ + t];
  qmL[t] = q_mask[b * NQ + t];
  const unsigned short* Arow = cw3T + ((size_t)b * NC + i0) * ND;
  const unsigned short* Brow = qT + (size_t)b * NQ * ND;
  f32x4 acc[4][4] = {};
  #pragma unroll
  for (int ks = 0; ks < 4; ++ks) {
    int g = ks * 4 + h;
    int off = ((g & 8) | ((g & 7) ^ (lr & 7))) * 8;
    bf16x8 a[4], bq[4];
    #pragma unroll
    for (int mi = 0; mi < 4; ++mi)
      a[mi] = *(const bf16x8*)&Arow[(size_t)(mi * 16 + lr) * ND + off];
    #pragma unroll
    for (int nf = 0; nf < 4; ++nf)
      bq[nf] = *(const bf16x8*)&Brow[(size_t)(wj + nf * 16 + lr) * ND + off];
    #pragma unroll
    for (int mi = 0; mi < 4; ++mi)
      #pragma unroll
      for (int nf = 0; nf < 4; ++nf)
        acc[mi][nf] = __builtin_amdgcn_mfma_f32_16x16x32_bf16(a[mi], bq[nf], acc[mi][nf], 0, 0, 0);
  }
  __syncthreads();
  float qbv[4], qmv[4];
  #pragma unroll
  for (int nf = 0; nf < 4; ++nf) {
    int j = wj + nf * 16 + lr;
    qbv[nf] = qbL[j]; qmv[nf] = qmL[j];
  }
  float rmv[4][4], rsv[4][4];
  #pragma unroll
  for (int mi = 0; mi < 4; ++mi)
    #pragma unroll
    for (int r = 0; r < 4; ++r) { rmv[mi][r] = -3.0e38f; rsv[mi][r] = 0.f; }
  #pragma unroll
  for (int mi = 0; mi < 4; ++mi) {
    #pragma unroll
    for (int r = 0; r < 4; ++r) {
      int row = mi * 16 + h * 4 + r;
      float cbr = cbL[row];
      #pragma unroll
      for (int nf = 0; nf < 4; ++nf) {
        float sv = acc[mi][nf][r] + cbr + qbv[nf];
        acc[mi][nf][r] = sv;
        float vq = sv * qmv[nf] + NEGV * (1.f - qmv[nf]);
        float mn = fmaxf(rmv[mi][r], vq);
        rsv[mi][r] = rsv[mi][r] * __expf(rmv[mi][r] - mn) + __expf(vq - mn);
        rmv[mi][r] = mn;
      }
    }
  }
  #pragma unroll
  for (int off = 1; off < 16; off <<= 1) {
    #pragma unroll
    for (int mi = 0; mi < 4; ++mi)
      #pragma unroll
      for (int r = 0; r < 4; ++r) {
        float mo = __shfl_xor(rmv[mi][r], off);
        float so = __shfl_xor(rsv[mi][r], off);
        float mn = fmaxf(rmv[mi][r], mo);
        rsv[mi][r] = rsv[mi][r] * __expf(rmv[mi][r] - mn) + so * __expf(mo - mn);
        rmv[mi][r] = mn;
      }
  }
  if (lr == 0) {
    #pragma unroll
    for (int mi = 0; mi < 4; ++mi)
      #pragma unroll
      for (int r = 0; r < 4; ++r) {
        rmP[mi * 16 + h * 4 + r][w] = rmv[mi][r];
        rsP[mi * 16 + h * 4 + r][w] = rsv[mi][r];
      }
  }
  float pm[4], ps[4];
  #pragma unroll
  for (int nf = 0; nf < 4; ++nf) { pm[nf] = -3.0e38f; ps[nf] = 0.f; }
  #pragma unroll
  for (int mi = 0; mi < 4; ++mi)
    #pragma unroll
    for (int r = 0; r < 4; ++r) {
      int row = mi * 16 + h * 4 + r;
      float cm = cmL[row];
      float cbias = NEGV * (1.f - cm);
      #pragma unroll
      for (int nf = 0; nf < 4; ++nf) {
        float v = acc[mi][nf][r] * cm + cbias;
        float mn = fmaxf(pm[nf], v);
        ps[nf] = ps[nf] * __expf(pm[nf] - mn) + __expf(v - mn);
        pm[nf] = mn;
      }
    }
  #pragma unroll
  for (int off = 16; off < 64; off <<= 1) {
    #pragma unroll
    for (int nf = 0; nf < 4; ++nf) {
      float mo = __shfl_xor(pm[nf], off);
      float so = __shfl_xor(ps[nf], off);
      float mn = fmaxf(pm[nf], mo);
      ps[nf] = ps[nf] * __expf(pm[nf] - mn) + so * __expf(mo - mn);
      pm[nf] = mn;
    }
  }
  if (h == 0) {
    #pragma unroll
    for (int nf = 0; nf < 4; ++nf) {
      int j = wj + nf * 16 + lr;
      colPm[((size_t)blockIdx.x * NB + b) * NQ + j] = pm[nf];
      colPs[((size_t)blockIdx.x * NB + b) * NQ + j] = ps[nf];
    }
  }
  __syncthreads();
  if (t < 64) {
    float m = rmP[t][0], s = rsP[t][0];
    #pragma unroll
    for (int k = 1; k < 4; ++k) {
      float mo = rmP[t][k], so = rsP[t][k];
      float mn = fmaxf(m, mo);
      s = s * __expf(m - mn) + so * __expf(mo - mn);
      m = mn;
    }
    rowmax[b * NC + i0 + t] = m;
    rowsum[b * NC + i0 + t] = s;
  }
}

// ---------------- k4f: fused S -> P_bbar^T -> inner (split-i 2). Block: 128d x 32j.
__global__ __launch_bounds__(256) void k4f(const unsigned short* __restrict__ cw3T,
                                           const unsigned short* __restrict__ qT,
                                           const unsigned short* __restrict__ cSwz,
                                           const float* __restrict__ cb, const float* __restrict__ qb,
                                           const float* __restrict__ c_mask,
                                           const float* __restrict__ colPm, const float* __restrict__ colPs,
                                           float* __restrict__ partial) {
  __shared__ unsigned short Pt[32 * 72];     // P^T operand, padded rows
  __shared__ float cmxL[32], cinvL[32], qbL2[32], cbL[64], cmL[64];
  int b = blockIdx.y;
  int jt = blockIdx.x & 7, split = blockIdx.x >> 3;
  int j0 = jt * 32;
  int t = threadIdx.x, w = t >> 6, l = t & 63, h = l >> 4, lr = l & 15;
  if (t < 32) {
    float m = -3.0e38f, s = 0.f;
    #pragma unroll
    for (int tl = 0; tl < 16; ++tl) {
      float mo = colPm[((size_t)tl * NB + b) * NQ + j0 + t];
      float so = colPs[((size_t)tl * NB + b) * NQ + j0 + t];
      float mn = fmaxf(m, mo);
      s = s * __expf(m - mn) + so * __expf(mo - mn);
      m = mn;
    }
    cmxL[t] = m;
    cinvL[t] = 1.0f / s;
    qbL2[t] = qb[b * NQ + j0 + t];
  }
  const unsigned short* Ab = cw3T + (size_t)b * NC * ND;
  const unsigned short* Bb = qT + ((size_t)b * NQ + j0) * ND;
  const unsigned short* Cb2 = cSwz + (size_t)b * ND * NC;
  f32x4 accI[2][2] = {};
  for (int ic8 = 0; ic8 < 8; ++ic8) {
    int ic = split * 512 + ic8 * 64;
    if (t < 64) { cbL[t] = cb[b * NC + ic + t]; cmL[t] = c_mask[b * NC + ic + t]; }
    __syncthreads();
    // phase A: S chunk [64i x 32j], frags direct from global
    f32x4 sA[2] = {};
    #pragma unroll
    for (int ks = 0; ks < 4; ++ks) {
      int g = ks * 4 + h;
      int off = ((g & 8) | ((g & 7) ^ (lr & 7))) * 8;
      bf16x8 av = *(const bf16x8*)&Ab[(size_t)(ic + w * 16 + lr) * ND + off];
      #pragma unroll
      for (int jf = 0; jf < 2; ++jf) {
        bf16x8 bv = *(const bf16x8*)&Bb[(size_t)(jf * 16 + lr) * ND + off];
        sA[jf] = __builtin_amdgcn_mfma_f32_16x16x32_bf16(av, bv, sA[jf], 0, 0, 0);
      }
    }
    #pragma unroll
    for (int jf = 0; jf < 2; ++jf)
      #pragma unroll
      for (int r = 0; r < 4; ++r) {
        int i_ = w * 16 + h * 4 + r;
        int j_ = jf * 16 + lr;
        float sfull = sA[jf][r] + cbL[i_] + qbL2[j_];
        float cm = cmL[i_];
        float vc = sfull * cm + NEGV * (1.f - cm);
        float p = __expf(vc - cmxL[j_]) * cinvL[j_];
        Pt[j_ * 72 + (((i_ >> 3) ^ (j_ & 7)) << 3) + (i_ & 7)] = f2bf(p);
      }
    __syncthreads();
    // phase B: inner += C x P^T (C frags direct from global)
    #pragma unroll
    for (int ks = 0; ks < 2; ++ks) {
      bf16x8 aC[2], bP[2];
      #pragma unroll
      for (int mf = 0; mf < 2; ++mf) {
        int d = w * 32 + mf * 16 + lr;
        aC[mf] = *(const bf16x8*)&Cb2[(size_t)d * NC + ic + (((ks * 4 + h) ^ (lr & 7)) * 8)];
      }
      #pragma unroll
      for (int jf = 0; jf < 2; ++jf) {
        int j_ = jf * 16 + lr;
        bP[jf] = *(const bf16x8*)&Pt[j_ * 72 + (((ks * 4 + h) ^ (j_ & 7)) * 8)];
      }
      #pragma unroll
      for (int mf = 0; mf < 2; ++mf)
        #pragma unroll
        for (int jf = 0; jf < 2; ++jf)
          accI[mf][jf] = __builtin_amdgcn_mfma_f32_16x16x32_bf16(aC[mf], bP[jf], accI[mf][jf], 0, 0, 0);
    }
  }
  float* pout = partial + ((size_t)(split * NB + b) * ND) * NQ;
  #pragma unroll
  for (int mf = 0; mf < 2; ++mf)
    #pragma unroll
    for (int jf = 0; jf < 2; ++jf)
      #pragma unroll
      for (int r = 0; r < 4; ++r) {
        int d = w * 32 + mf * 16 + h * 4 + r;
        int j = j0 + jf * 16 + lr;
        pout[(size_t)d * NQ + j] = accI[mf][jf][r];
      }
}

// ---------------- k5f: fused S -> P_bar -> {A, Bm} -> concat x (bf16). Block: 32i x 128d.
// Inner B-operand combines the 2 split-K partials inline (bit-identical to old k4c2 path).
__global__ __launch_bounds__(256) void k5f(const unsigned short* __restrict__ cw3T,
                                           const unsigned short* __restrict__ qT,
                                           const unsigned short* __restrict__ qSwz,
                                           const float* __restrict__ partial,
                                           const float* __restrict__ C,
                                           const float* __restrict__ cb, const float* __restrict__ qb,
                                           const float* __restrict__ q_mask,
                                           const float* __restrict__ rowmax, const float* __restrict__ rowsum,
                                           unsigned short* __restrict__ xB) {
  extern __shared__ char sm[];
  unsigned short* cwA = (unsigned short*)sm;            // [32][128] 8KB
  unsigned short* Pl = (unsigned short*)(sm + 8192);    // [32][72] 4.6KB
  float* As = (float*)sm;                               // epilogue alias [32][133]
  float* Bs = (float*)(sm + 17024);
  __shared__ float rmL[32], riL[32], cbI[32], qbL[256], qmL[256];
  int b = blockIdx.y, i0 = blockIdx.x * 32;
  int t = threadIdx.x, w = t >> 6, l = t & 63, h = l >> 4, lr = l & 15;
  {
    const unsigned short* src = cw3T + ((size_t)b * NC + i0) * ND;   // 32x128 contiguous
    #pragma unroll
    for (int k = 0; k < 2; ++k) {
      int u = t + k * 256;
      *(u16x8*)&cwA[u * 8] = *(const u16x8*)(src + u * 8);
    }
  }
  if (t < 32) {
    rmL[t] = rowmax[b * NC + i0 + t];
    riL[t] = 1.0f / rowsum[b * NC + i0 + t];
    cbI[t] = cb[b * NC + i0 + t];
  }
  qbL[t] = qb[b * NQ + t];
  qmL[t] = q_mask[b * NQ + t];
  __syncthreads();

  const unsigned short* qTb = qT + (size_t)b * NQ * ND;
  const unsigned short* qSb = qSwz + (size_t)b * ND * NQ;
  const float* iP0 = partial + (size_t)b * ND * NQ;
  const float* iP1 = partial + ((size_t)(NB + b)) * ND * NQ;
  f32x4 accA[2][2] = {};
  f32x4 accB[2][2] = {};

  for (int jc = 0; jc < 4; ++jc) {
    int j0 = jc * 64;
    f32x4 sA[2] = {};
    #pragma unroll
    for (int ks = 0; ks < 4; ++ks) {
      int g = ks * 4 + h;
      int off = ((g & 8) | ((g & 7) ^ (lr & 7))) * 8;
      bf16x8 bv = *(const bf16x8*)&qTb[(size_t)(j0 + w * 16 + lr) * ND + off];
      #pragma unroll
      for (int mi = 0; mi < 2; ++mi) {
        bf16x8 av = *(const bf16x8*)&cwA[(mi * 16 + lr) * 128 + off];
        sA[mi] = __builtin_amdgcn_mfma_f32_16x16x32_bf16(av, bv, sA[mi], 0, 0, 0);
      }
    }
    #pragma unroll
    for (int mi = 0; mi < 2; ++mi)
      #pragma unroll
      for (int r = 0; r < 4; ++r) {
        int i_ = mi * 16 + h * 4 + r;
        int j_ = w * 16 + lr;
        float sfull = sA[mi][r] + cbI[i_] + qbL[j0 + j_];
        float qm = qmL[j0 + j_];
        float vq = sfull * qm + NEGV * (1.f - qm);
        float p = __expf(vq - rmL[i_]) * riL[i_];
        Pl[i_ * 72 + (((j_ >> 3) ^ (i_ & 7)) << 3) + (j_ & 7)] = f2bf(p);
      }
    __syncthreads();
    #pragma unroll
    for (int ks = 0; ks < 2; ++ks) {
      int jbase = j0 + (ks * 4 + h) * 8;
      bf16x8 aP[2], bQ[2], bI[2];
      #pragma unroll
      for (int mi = 0; mi < 2; ++mi) {
        int i = mi * 16 + lr;
        int slot = (ks * 4 + h) ^ (i & 7);
        aP[mi] = *(const bf16x8*)&Pl[i * 72 + slot * 8];
      }
      #pragma unroll
      for (int nd = 0; nd < 2; ++nd) {
        int d = w * 32 + nd * 16 + lr;
        int slot = (ks * 4 + h) ^ (d & 7);
        bQ[nd] = *(const bf16x8*)&qSb[(size_t)d * NQ + j0 + slot * 8];
        float4 p0a = *(const float4*)&iP0[(size_t)d * NQ + jbase];
        float4 p0b = *(const float4*)&iP0[(size_t)d * NQ + jbase + 4];
        float4 p1a = *(const float4*)&iP1[(size_t)d * NQ + jbase];
        float4 p1b = *(const float4*)&iP1[(size_t)d * NQ + jbase + 4];
        u16x8 bi;
        bi[0] = f2bf(p0a.x + p1a.x); bi[1] = f2bf(p0a.y + p1a.y);
        bi[2] = f2bf(p0a.z + p1a.z); bi[3] = f2bf(p0a.w + p1a.w);
        bi[4] = f2bf(p0b.x + p1b.x); bi[5] = f2bf(p0b.y + p1b.y);
        bi[6] = f2bf(p0b.z + p1b.z); bi[7] = f2bf(p0b.w + p1b.w);
        bI[nd] = __builtin_bit_cast(bf16x8, bi);
      }
      #pragma unroll
      for (int mi = 0; mi < 2; ++mi)
        #pragma unroll
        for (int nd = 0; nd < 2; ++nd) {
          accA[mi][nd] = __builtin_amdgcn_mfma_f32_16x16x32_bf16(aP[mi], bQ[nd], accA[mi][nd], 0, 0, 0);
          accB[mi][nd] = __builtin_amdgcn_mfma_f32_16x16x32_bf16(aP[mi], bI[nd], accB[mi][nd], 0, 0, 0);
        }
    }
    __syncthreads();
  }
  // epilogue (aliases cwA/Pl region)
  #pragma unroll
  for (int mi = 0; mi < 2; ++mi)
    #pragma unroll
    for (int nd = 0; nd < 2; ++nd) {
      int d = w * 32 + nd * 16 + lr;
      #pragma unroll
      for (int r = 0; r < 4; ++r) {
        int i = mi * 16 + h * 4 + r;
        As[i * 133 + d] = accA[mi][nd][r];
        Bs[i * 133 + d] = accB[mi][nd][r];
      }
    }
  __syncthreads();
  {
    int i4 = (t & 7) * 4, db = t >> 3;
    const float* Cb = C + (size_t)b * ND * NC;
    unsigned short* xb = xB + (size_t)b * 4 * ND * NC;
    #pragma unroll
    for (int p = 0; p < 4; ++p) {
      int d = db + p * 32;
      float4 c4 = *(const float4*)&Cb[(size_t)d * NC + i0 + i4];
      float4 a4, b4;
      a4.x = As[(i4 + 0) * 133 + d]; a4.y = As[(i4 + 1) * 133 + d];
      a4.z = As[(i4 + 2) * 133 + d]; a4.w = As[(i4 + 3) * 133 + d];
      b4.x = Bs[(i4 + 0) * 133 + d]; b4.y = Bs[(i4 + 1) * 133 + d];
      b4.z = Bs[(i4 + 2) * 133 + d]; b4.w = Bs[(i4 + 3) * 133 + d];
      u16x4 o0, o1, o2, o3;
      o0[0] = f2bf(c4.x); o0[1] = f2bf(c4.y); o0[2] = f2bf(c4.z); o0[3] = f2bf(c4.w);
      o1[0] = f2bf(a4.x); o1[1] = f2bf(a4.y); o1[2] = f2bf(a4.z); o1[3] = f2bf(a4.w);
      o2[0] = f2bf(c4.x * a4.x); o2[1] = f2bf(c4.y * a4.y); o2[2] = f2bf(c4.z * a4.z); o2[3] = f2bf(c4.w * a4.w);
      o3[0] = f2bf(c4.x * b4.x); o3[1] = f2bf(c4.y * b4.y); o3[2] = f2bf(c4.z * b4.z); o3[3] = f2bf(c4.w * b4.w);
      *(u16x4*)&xb[(size_t)(0 * ND + d) * NC + i0 + i4] = o0;
      *(u16x4*)&xb[(size_t)(1 * ND + d) * NC + i0 + i4] = o1;
      *(u16x4*)&xb[(size_t)(2 * ND + d) * NC + i0 + i4] = o2;
      *(u16x4*)&xb[(size_t)(3 * ND + d) * NC + i0 + i4] = o3;
    }
  }
}

// ---------------- K6 (MFMA): depthwise(k=5,pad2) + pointwise GEMM (R9 proven version)
__global__ __launch_bounds__(256) void k6_mfma(const unsigned short* __restrict__ x,
                                               const float* __restrict__ dwW, const float* __restrict__ dwB,
                                               const unsigned short* __restrict__ pwB16,
                                               const float* __restrict__ pwB, float* __restrict__ out) {
  extern __shared__ char sm6[];
  unsigned short* xs = (unsigned short*)sm6;            // [64][56]
  unsigned short* x1s = (unsigned short*)(sm6 + 7168);  // [32][72]
  unsigned short* pws = (unsigned short*)(sm6 + 11776); // [128][72]
  int b = blockIdx.y, l0 = blockIdx.x * 32;
  int t = threadIdx.x, w = t >> 6, l = t & 63, h = l >> 4, lr = l & 15;
  const unsigned short* xb = x + (size_t)b * 4 * ND * NC;
  f32x4 acc[2][2] = {};
  int cgw = t & 63, lb = w * 8;

  for (int ch = 0; ch < 8; ++ch) {
    int cg0 = ch * 64;
    __syncthreads();
    #pragma unroll
    for (int k = 0; k < 2; ++k) {
      int id2 = t + k * 256;
      if (id2 < 384) {
        int row = id2 / 6, seg = id2 % 6;
        int gl = l0 - 8 + seg * 8;
        u16x8 v = {};
        if ((unsigned)gl <= 1016u)
          v = *(const u16x8*)(xb + (size_t)(cg0 + row) * NC + gl);
        *(u16x8*)&xs[row * 56 + seg * 8] = v;
      }
    }
    #pragma unroll
    for (int k = 0; k < 4; ++k) {
      int id2 = t + k * 256;
      int o = id2 >> 3, s8 = id2 & 7;
      *(u16x8*)&pws[o * 72 + s8 * 8] = *(const u16x8*)(pwB16 + (size_t)o * 512 + cg0 + s8 * 8);
    }
    __syncthreads();
    {
      int gch = cg0 + cgw;
      float bias = dwB[gch];
      float dwv[5];
      #pragma unroll
      for (int tp = 0; tp < 5; ++tp) dwv[tp] = dwW[gch * 5 + tp];
      float f[24];
      #pragma unroll
      for (int s = 0; s < 3; ++s) {
        u16x8 v = *(const u16x8*)&xs[cgw * 56 + lb + s * 8];
        #pragma unroll
        for (int e = 0; e < 8; ++e) f[s * 8 + e] = bf2f(v[e]);
      }
      #pragma unroll
      for (int e = 0; e < 8; ++e) {
        float a = bias;
        #pragma unroll
        for (int tp = 0; tp < 5; ++tp)
          a = fmaf(f[e + 6 + tp], dwv[tp], a);
        x1s[(lb + e) * 72 + cgw] = f2bf(a);
      }
    }
    __syncthreads();
    #pragma unroll
    for (int ks = 0; ks < 2; ++ks) {
      bf16x8 aW[2], bX[2];
      #pragma unroll
      for (int mi = 0; mi < 2; ++mi) {
        int o = w * 32 + mi * 16 + lr;
        aW[mi] = *(const bf16x8*)&pws[o * 72 + ks * 32 + h * 8];
      }
      #pragma unroll
      for (int nf = 0; nf < 2; ++nf) {
        int ll = nf * 16 + lr;
        bX[nf] = *(const bf16x8*)&x1s[ll * 72 + ks * 32 + h * 8];
      }
      #pragma unroll
      for (int mi = 0; mi < 2; ++mi)
        #pragma unroll
        for (int nf = 0; nf < 2; ++nf)
          acc[mi][nf] = __builtin_amdgcn_mfma_f32_16x16x32_bf16(aW[mi], bX[nf], acc[mi][nf], 0, 0, 0);
    }
  }
  #pragma unroll
  for (int mi = 0; mi < 2; ++mi) {
    #pragma unroll
    for (int r = 0; r < 4; ++r) {
      int o = w * 32 + mi * 16 + h * 4 + r;
      float bv = pwB[o];
      #pragma unroll
      for (int nf = 0; nf < 2; ++nf)
        out[((size_t)b * ND + o) * NC + l0 + nf * 16 + lr] = acc[mi][nf][r] + bv;
    }
  }
}

extern "C" void kernel_launch(void* const* d_in, const int* in_sizes, int n_in,
                              void* d_out, int out_size, void* d_ws, size_t ws_size,
                              hipStream_t stream) {
  const float* C = (const float*)d_in[0];
  const float* Q = (const float*)d_in[1];
  const float* c_mask = (const float*)d_in[2];
  const float* q_mask = (const float*)d_in[3];
  const float* W0 = (const float*)d_in[4];
  const float* dwW = (const float*)d_in[5];
  const float* dwB = (const float*)d_in[6];
  const float* pwW = (const float*)d_in[7];
  const float* pwB = (const float*)d_in[8];
  float* out = (float*)d_out;
  float* ws = (float*)d_ws;

  float* rowmax = ws;                                  // NB*NC
  float* rowsum = rowmax + NB * NC;
  float* colmax = rowsum + NB * NC;                    // (unused, layout keep)
  float* colsum = colmax + NB * NQ;
  float* cb = colsum + NB * NQ;                        // NB*NC
  float* qb = cb + NB * NC;                            // NB*NQ
  float* colPm = qb + NB * NQ;                         // 16*NB*NQ
  float* colPs = colPm + 16 * NB * NQ;                 // 16*NB*NQ
  unsigned short* qSwz = (unsigned short*)(colPs + 16 * NB * NQ);   // NB*ND*NQ
  unsigned short* qT = qSwz + (size_t)NB * ND * NQ;                 // NB*NQ*ND
  unsigned short* iSwz = qT + (size_t)NB * NQ * ND;                 // (unused, layout keep)
  unsigned short* cw3T = iSwz + (size_t)NB * ND * NQ;               // NB*NC*ND
  unsigned short* cSwz = cw3T + (size_t)NB * NC * ND;               // NB*ND*NC
  unsigned short* pwB16 = cSwz + (size_t)NB * ND * NC;              // 128*512
  float* partial = (float*)(pwB16 + ND * 512);                      // 2*NB*ND*NQ f32
  unsigned short* xB = (unsigned short*)(partial + 2 * (size_t)NB * ND * NQ);  // NB*4*ND*NC

  k_prep<<<dim3(672), 256, 0, stream>>>(C, Q, pwW, W0, cw3T, cSwz, cb, qSwz, qT, qb, pwB16);
  k_stats<<<dim3(16, NB), 256, 0, stream>>>(cw3T, qT, cb, qb, q_mask, c_mask, rowmax, rowsum, colPm, colPs);
  k4f<<<dim3(16, NB), 256, 0, stream>>>(cw3T, qT, cSwz, cb, qb, c_mask, colPm, colPs, partial);
  k5f<<<dim3(NC / 32, NB), 256, 34048, stream>>>(cw3T, qT, qSwz, partial, C, cb, qb, q_mask, rowmax, rowsum, xB);
  k6_mfma<<<dim3(NC / 32, NB), 256, 30208, stream>>>(xB, dwW, dwB, pwB16, pwB, out);
}

// Round 17
// 109.756 us; speedup vs baseline: 1.2698x; 1.2698x over previous
//
#include <hip/hip_runtime.h>
#include <math.h>

#define NB 32
#define ND 128
#define NC 1024
#define NQ 256
#define NEGV (-1e30f)

typedef __attribute__((ext_vector_type(8))) __bf16 bf16x8;
typedef __attribute__((ext_vector_type(4))) float f32x4;
typedef __attribute__((ext_vector_type(8))) unsigned short u16x8;
typedef __attribute__((ext_vector_type(4))) unsigned short u16x4;

__device__ inline unsigned short f2bf(float f) {
  unsigned u = __builtin_bit_cast(unsigned, f);
  u += 0x7FFFu + ((u >> 16) & 1u);
  return (unsigned short)(u >> 16);
}
__device__ inline float bf2f(unsigned short u) {
  return __builtin_bit_cast(float, (unsigned)u << 16);
}

// ---------------- k_prep: fused {cprep | qprep | pwcvt} dispatcher (1-D grid 672)
__global__ __launch_bounds__(256) void k_prep(const float* __restrict__ C, const float* __restrict__ Q,
                                              const float* __restrict__ pwW, const float* __restrict__ W0,
                                              unsigned short* __restrict__ cw3T, unsigned short* __restrict__ cSwz,
                                              float* __restrict__ cb,
                                              unsigned short* __restrict__ qSwz, unsigned short* __restrict__ qT,
                                              float* __restrict__ qb,
                                              unsigned short* __restrict__ pwB16) {
  __shared__ unsigned short T2[128 * 66];
  __shared__ float wA[128], wB[128];
  __shared__ float redP[4][64];
  int bid = blockIdx.x, t = threadIdx.x;
  if (bid < 512) {
    // ---- cprep
    int b = bid >> 4, tile = bid & 15, i0 = tile * 64;
    if (t < 128) { wA[t] = W0[t]; wB[t] = W0[2 * ND + t]; }
    int k = t >> 1, half = t & 1;
    const float* src = C + ((size_t)b * ND + k) * NC + i0 + half * 32;
    unsigned short* cdst = cSwz + ((size_t)b * ND + k) * NC + tile * 64;
    #pragma unroll
    for (int q = 0; q < 4; ++q) {
      float4 v0 = ((const float4*)src)[q * 2];
      float4 v1 = ((const float4*)src)[q * 2 + 1];
      u16x8 o;
      o[0] = f2bf(v0.x); o[1] = f2bf(v0.y); o[2] = f2bf(v0.z); o[3] = f2bf(v0.w);
      o[4] = f2bf(v1.x); o[5] = f2bf(v1.y); o[6] = f2bf(v1.z); o[7] = f2bf(v1.w);
      *(u16x8*)&T2[k * 66 + half * 32 + q * 8] = o;
      int g = half * 4 + q;
      *(u16x8*)&cdst[(g ^ (k & 7)) * 8] = o;
    }
    __syncthreads();
    {
      int ii = t & 63, kq = t >> 6;
      float s = 0.f;
      #pragma unroll 8
      for (int kk = 0; kk < 32; ++kk) {
        int dd = kq * 32 + kk;
        s += bf2f(T2[dd * 66 + ii]) * wA[dd];
      }
      redP[kq][ii] = s;
    }
    __syncthreads();
    if (t < 64)
      cb[b * NC + i0 + t] = redP[0][t] + redP[1][t] + redP[2][t] + redP[3][t];
    {
      int ii = t >> 2, p = t & 3;
      unsigned short* dst = cw3T + ((size_t)b * NC + i0 + ii) * ND;
      #pragma unroll
      for (int q = 0; q < 4; ++q) {
        int g = p * 4 + q;
        u16x8 o;
        #pragma unroll
        for (int e = 0; e < 8; ++e)
          o[e] = f2bf(bf2f(T2[(g * 8 + e) * 66 + ii]) * wB[g * 8 + e]);
        int sg = (g & 8) | ((g & 7) ^ (ii & 7));
        *(u16x8*)&dst[sg * 8] = o;
      }
    }
  } else if (bid < 640) {
    // ---- qprep
    int r = bid - 512, b = r >> 2, jc = r & 3, j0 = jc * 64;
    if (t < 128) wA[t] = W0[ND + t];
    int d = t >> 1, half = t & 1;
    const float* src = Q + ((size_t)b * ND + d) * NQ + j0 + half * 32;
    unsigned short* qdst = qSwz + ((size_t)b * ND + d) * NQ + jc * 64;
    #pragma unroll
    for (int q = 0; q < 4; ++q) {
      float4 v0 = ((const float4*)src)[q * 2];
      float4 v1 = ((const float4*)src)[q * 2 + 1];
      u16x8 o;
      o[0] = f2bf(v0.x); o[1] = f2bf(v0.y); o[2] = f2bf(v0.z); o[3] = f2bf(v0.w);
      o[4] = f2bf(v1.x); o[5] = f2bf(v1.y); o[6] = f2bf(v1.z); o[7] = f2bf(v1.w);
      *(u16x8*)&T2[d * 66 + half * 32 + q * 8] = o;
      int g = half * 4 + q;
      *(u16x8*)&qdst[(g ^ (d & 7)) * 8] = o;
    }
    __syncthreads();
    {
      int jj = t & 63, dq = t >> 6;
      float s = 0.f;
      #pragma unroll 8
      for (int k = 0; k < 32; ++k) {
        int dd = dq * 32 + k;
        s += bf2f(T2[dd * 66 + jj]) * wA[dd];
      }
      redP[dq][jj] = s;
    }
    __syncthreads();
    if (t < 64)
      qb[b * NQ + j0 + t] = redP[0][t] + redP[1][t] + redP[2][t] + redP[3][t];
    {
      int jj = t >> 2, p = t & 3;
      unsigned short* dst = qT + ((size_t)b * NQ + j0 + jj) * ND;
      #pragma unroll
      for (int q = 0; q < 4; ++q) {
        int g = p * 4 + q;
        u16x8 o;
        #pragma unroll
        for (int e = 0; e < 8; ++e) o[e] = T2[(g * 8 + e) * 66 + jj];
        int sg = (g & 8) | ((g & 7) ^ (jj & 7));
        *(u16x8*)&dst[sg * 8] = o;
      }
    }
  } else {
    // ---- pwcvt
    int idx = (bid - 640) * 256 + t;   // 0..8191
    const float4* src = (const float4*)pwW;
    float4 v0 = src[idx * 2], v1 = src[idx * 2 + 1];
    u16x8 o;
    o[0] = f2bf(v0.x); o[1] = f2bf(v0.y); o[2] = f2bf(v0.z); o[3] = f2bf(v0.w);
    o[4] = f2bf(v1.x); o[5] = f2bf(v1.y); o[6] = f2bf(v1.z); o[7] = f2bf(v1.w);
    ((u16x8*)pwB16)[idx] = o;
  }
}

// ---------------- k_stats: MFMA S + full row stats + col partials. Tile 64i x 256j.
__global__ __launch_bounds__(256) void k_stats(const unsigned short* __restrict__ cw3T,
                                               const unsigned short* __restrict__ qT,
                                               const float* __restrict__ cb, const float* __restrict__ qb,
                                               const float* __restrict__ q_mask, const float* __restrict__ c_mask,
                                               float* __restrict__ rowmax, float* __restrict__ rowsum,
                                               float* __restrict__ colPm, float* __restrict__ colPs) {
  __shared__ float rmP[64][4], rsP[64][4];
  __shared__ float cbL[64], cmL[64], qbL[256], qmL[256];
  int b = blockIdx.y, i0 = blockIdx.x * 64;
  int t = threadIdx.x, w = t >> 6, l = t & 63, h = l >> 4, lr = l & 15;
  int wj = w * 64;
  if (t < 64) { cbL[t] = cb[b * NC + i0 + t]; cmL[t] = c_mask[b * NC + i0 + t]; }
  qbL[t] = qb[b * NQ + t];
  qmL[t] = q_mask[b * NQ + t];
  const unsigned short* Arow = cw3T + ((size_t)b * NC + i0) * ND;
  const unsigned short* Brow = qT + (size_t)b * NQ * ND;
  f32x4 acc[4][4] = {};
  #pragma unroll
  for (int ks = 0; ks < 4; ++ks) {
    int g = ks * 4 + h;
    int off = ((g & 8) | ((g & 7) ^ (lr & 7))) * 8;
    bf16x8 a[4], bq[4];
    #pragma unroll
    for (int mi = 0; mi < 4; ++mi)
      a[mi] = *(const bf16x8*)&Arow[(size_t)(mi * 16 + lr) * ND + off];
    #pragma unroll
    for (int nf = 0; nf < 4; ++nf)
      bq[nf] = *(const bf16x8*)&Brow[(size_t)(wj + nf * 16 + lr) * ND + off];
    #pragma unroll
    for (int mi = 0; mi < 4; ++mi)
      #pragma unroll
      for (int nf = 0; nf < 4; ++nf)
        acc[mi][nf] = __builtin_amdgcn_mfma_f32_16x16x32_bf16(a[mi], bq[nf], acc[mi][nf], 0, 0, 0);
  }
  __syncthreads();
  float qbv[4], qmv[4];
  #pragma unroll
  for (int nf = 0; nf < 4; ++nf) {
    int j = wj + nf * 16 + lr;
    qbv[nf] = qbL[j]; qmv[nf] = qmL[j];
  }
  float rmv[4][4], rsv[4][4];
  #pragma unroll
  for (int mi = 0; mi < 4; ++mi)
    #pragma unroll
    for (int r = 0; r < 4; ++r) { rmv[mi][r] = -3.0e38f; rsv[mi][r] = 0.f; }
  #pragma unroll
  for (int mi = 0; mi < 4; ++mi) {
    #pragma unroll
    for (int r = 0; r < 4; ++r) {
      int row = mi * 16 + h * 4 + r;
      float cbr = cbL[row];
      #pragma unroll
      for (int nf = 0; nf < 4; ++nf) {
        float sv = acc[mi][nf][r] + cbr + qbv[nf];
        acc[mi][nf][r] = sv;
        float vq = sv * qmv[nf] + NEGV * (1.f - qmv[nf]);
        float mn = fmaxf(rmv[mi][r], vq);
        rsv[mi][r] = rsv[mi][r] * __expf(rmv[mi][r] - mn) + __expf(vq - mn);
        rmv[mi][r] = mn;
      }
    }
  }
  #pragma unroll
  for (int off = 1; off < 16; off <<= 1) {
    #pragma unroll
    for (int mi = 0; mi < 4; ++mi)
      #pragma unroll
      for (int r = 0; r < 4; ++r) {
        float mo = __shfl_xor(rmv[mi][r], off);
        float so = __shfl_xor(rsv[mi][r], off);
        float mn = fmaxf(rmv[mi][r], mo);
        rsv[mi][r] = rsv[mi][r] * __expf(rmv[mi][r] - mn) + so * __expf(mo - mn);
        rmv[mi][r] = mn;
      }
  }
  if (lr == 0) {
    #pragma unroll
    for (int mi = 0; mi < 4; ++mi)
      #pragma unroll
      for (int r = 0; r < 4; ++r) {
        rmP[mi * 16 + h * 4 + r][w] = rmv[mi][r];
        rsP[mi * 16 + h * 4 + r][w] = rsv[mi][r];
      }
  }
  float pm[4], ps[4];
  #pragma unroll
  for (int nf = 0; nf < 4; ++nf) { pm[nf] = -3.0e38f; ps[nf] = 0.f; }
  #pragma unroll
  for (int mi = 0; mi < 4; ++mi)
    #pragma unroll
    for (int r = 0; r < 4; ++r) {
      int row = mi * 16 + h * 4 + r;
      float cm = cmL[row];
      float cbias = NEGV * (1.f - cm);
      #pragma unroll
      for (int nf = 0; nf < 4; ++nf) {
        float v = acc[mi][nf][r] * cm + cbias;
        float mn = fmaxf(pm[nf], v);
        ps[nf] = ps[nf] * __expf(pm[nf] - mn) + __expf(v - mn);
        pm[nf] = mn;
      }
    }
  #pragma unroll
  for (int off = 16; off < 64; off <<= 1) {
    #pragma unroll
    for (int nf = 0; nf < 4; ++nf) {
      float mo = __shfl_xor(pm[nf], off);
      float so = __shfl_xor(ps[nf], off);
      float mn = fmaxf(pm[nf], mo);
      ps[nf] = ps[nf] * __expf(pm[nf] - mn) + so * __expf(mo - mn);
      pm[nf] = mn;
    }
  }
  if (h == 0) {
    #pragma unroll
    for (int nf = 0; nf < 4; ++nf) {
      int j = wj + nf * 16 + lr;
      colPm[((size_t)blockIdx.x * NB + b) * NQ + j] = pm[nf];
      colPs[((size_t)blockIdx.x * NB + b) * NQ + j] = ps[nf];
    }
  }
  __syncthreads();
  if (t < 64) {
    float m = rmP[t][0], s = rsP[t][0];
    #pragma unroll
    for (int k = 1; k < 4; ++k) {
      float mo = rmP[t][k], so = rsP[t][k];
      float mn = fmaxf(m, mo);
      s = s * __expf(m - mn) + so * __expf(mo - mn);
      m = mn;
    }
    rowmax[b * NC + i0 + t] = m;
    rowsum[b * NC + i0 + t] = s;
  }
}

// ---------------- k4f: fused S -> P_bbar^T -> inner (split-i 2). Block: 128d x 32j.
__global__ __launch_bounds__(256) void k4f(const unsigned short* __restrict__ cw3T,
                                           const unsigned short* __restrict__ qT,
                                           const unsigned short* __restrict__ cSwz,
                                           const float* __restrict__ cb, const float* __restrict__ qb,
                                           const float* __restrict__ c_mask,
                                           const float* __restrict__ colPm, const float* __restrict__ colPs,
                                           float* __restrict__ partial) {
  __shared__ unsigned short Pt[32 * 72];     // P^T operand, padded rows
  __shared__ float cmxL[32], cinvL[32], qbL2[32], cbL[64], cmL[64];
  int b = blockIdx.y;
  int jt = blockIdx.x & 7, split = blockIdx.x >> 3;
  int j0 = jt * 32;
  int t = threadIdx.x, w = t >> 6, l = t & 63, h = l >> 4, lr = l & 15;
  if (t < 32) {
    float m = -3.0e38f, s = 0.f;
    #pragma unroll
    for (int tl = 0; tl < 16; ++tl) {
      float mo = colPm[((size_t)tl * NB + b) * NQ + j0 + t];
      float so = colPs[((size_t)tl * NB + b) * NQ + j0 + t];
      float mn = fmaxf(m, mo);
      s = s * __expf(m - mn) + so * __expf(mo - mn);
      m = mn;
    }
    cmxL[t] = m;
    cinvL[t] = 1.0f / s;
    qbL2[t] = qb[b * NQ + j0 + t];
  }
  const unsigned short* Ab = cw3T + (size_t)b * NC * ND;
  const unsigned short* Bb = qT + ((size_t)b * NQ + j0) * ND;
  const unsigned short* Cb2 = cSwz + (size_t)b * ND * NC;
  f32x4 accI[2][2] = {};
  for (int ic8 = 0; ic8 < 8; ++ic8) {
    int ic = split * 512 + ic8 * 64;
    if (t < 64) { cbL[t] = cb[b * NC + ic + t]; cmL[t] = c_mask[b * NC + ic + t]; }
    __syncthreads();
    f32x4 sA[2] = {};
    #pragma unroll
    for (int ks = 0; ks < 4; ++ks) {
      int g = ks * 4 + h;
      int off = ((g & 8) | ((g & 7) ^ (lr & 7))) * 8;
      bf16x8 av = *(const bf16x8*)&Ab[(size_t)(ic + w * 16 + lr) * ND + off];
      #pragma unroll
      for (int jf = 0; jf < 2; ++jf) {
        bf16x8 bv = *(const bf16x8*)&Bb[(size_t)(jf * 16 + lr) * ND + off];
        sA[jf] = __builtin_amdgcn_mfma_f32_16x16x32_bf16(av, bv, sA[jf], 0, 0, 0);
      }
    }
    #pragma unroll
    for (int jf = 0; jf < 2; ++jf)
      #pragma unroll
      for (int r = 0; r < 4; ++r) {
        int i_ = w * 16 + h * 4 + r;
        int j_ = jf * 16 + lr;
        float sfull = sA[jf][r] + cbL[i_] + qbL2[j_];
        float cm = cmL[i_];
        float vc = sfull * cm + NEGV * (1.f - cm);
        float p = __expf(vc - cmxL[j_]) * cinvL[j_];
        Pt[j_ * 72 + (((i_ >> 3) ^ (j_ & 7)) << 3) + (i_ & 7)] = f2bf(p);
      }
    __syncthreads();
    #pragma unroll
    for (int ks = 0; ks < 2; ++ks) {
      bf16x8 aC[2], bP[2];
      #pragma unroll
      for (int mf = 0; mf < 2; ++mf) {
        int d = w * 32 + mf * 16 + lr;
        aC[mf] = *(const bf16x8*)&Cb2[(size_t)d * NC + ic + (((ks * 4 + h) ^ (lr & 7)) * 8)];
      }
      #pragma unroll
      for (int jf = 0; jf < 2; ++jf) {
        int j_ = jf * 16 + lr;
        bP[jf] = *(const bf16x8*)&Pt[j_ * 72 + (((ks * 4 + h) ^ (j_ & 7)) * 8)];
      }
      #pragma unroll
      for (int mf = 0; mf < 2; ++mf)
        #pragma unroll
        for (int jf = 0; jf < 2; ++jf)
          accI[mf][jf] = __builtin_amdgcn_mfma_f32_16x16x32_bf16(aC[mf], bP[jf], accI[mf][jf], 0, 0, 0);
    }
  }
  float* pout = partial + ((size_t)(split * NB + b) * ND) * NQ;
  #pragma unroll
  for (int mf = 0; mf < 2; ++mf)
    #pragma unroll
    for (int jf = 0; jf < 2; ++jf)
      #pragma unroll
      for (int r = 0; r < 4; ++r) {
        int d = w * 32 + mf * 16 + h * 4 + r;
        int j = j0 + jf * 16 + lr;
        pout[(size_t)d * NQ + j] = accI[mf][jf][r];
      }
}

// ---------------- k4c2: combine 2 split partials -> bf16 iSwz (pre-swizzled)
__global__ __launch_bounds__(256) void k4c2(const float* __restrict__ partial,
                                            unsigned short* __restrict__ iSwz) {
  int idx = blockIdx.x * 256 + threadIdx.x;   // over NB*ND*NQ/4
  const size_t n = (size_t)NB * ND * NQ / 4;
  const float4* p = (const float4*)partial;
  float4 a = p[idx], b4 = p[n + idx];
  u16x4 o;
  o[0] = f2bf(a.x + b4.x);
  o[1] = f2bf(a.y + b4.y);
  o[2] = f2bf(a.z + b4.z);
  o[3] = f2bf(a.w + b4.w);
  int lin = idx * 4;
  int j = lin & 255, dd = (lin >> 8) & 127, bb = lin >> 15;
  int g = (j >> 3) & 7, e0 = j & 7;
  int outoff = ((bb * 128 + dd) << 8) + (j & 192) + ((g ^ (dd & 7)) << 3) + e0;
  *(u16x4*)&iSwz[outoff] = o;
}

// ---------------- k5f: fused S -> P_bar -> {A, Bm} -> concat x (bf16). Block: 32i x 128d.
__global__ __launch_bounds__(256) void k5f(const unsigned short* __restrict__ cw3T,
                                           const unsigned short* __restrict__ qT,
                                           const unsigned short* __restrict__ qSwz,
                                           const unsigned short* __restrict__ iSwz,
                                           const float* __restrict__ C,
                                           const float* __restrict__ cb, const float* __restrict__ qb,
                                           const float* __restrict__ q_mask,
                                           const float* __restrict__ rowmax, const float* __restrict__ rowsum,
                                           unsigned short* __restrict__ xB) {
  extern __shared__ char sm[];
  unsigned short* cwA = (unsigned short*)sm;            // [32][128] 8KB
  unsigned short* Pl = (unsigned short*)(sm + 8192);    // [32][72] 4.6KB
  float* As = (float*)sm;                               // epilogue alias [32][133]
  float* Bs = (float*)(sm + 17024);
  __shared__ float rmL[32], riL[32], cbI[32], qbL[256], qmL[256];
  int b = blockIdx.y, i0 = blockIdx.x * 32;
  int t = threadIdx.x, w = t >> 6, l = t & 63, h = l >> 4, lr = l & 15;
  {
    const unsigned short* src = cw3T + ((size_t)b * NC + i0) * ND;   // 32x128 contiguous
    #pragma unroll
    for (int k = 0; k < 2; ++k) {
      int u = t + k * 256;
      *(u16x8*)&cwA[u * 8] = *(const u16x8*)(src + u * 8);
    }
  }
  if (t < 32) {
    rmL[t] = rowmax[b * NC + i0 + t];
    riL[t] = 1.0f / rowsum[b * NC + i0 + t];
    cbI[t] = cb[b * NC + i0 + t];
  }
  qbL[t] = qb[b * NQ + t];
  qmL[t] = q_mask[b * NQ + t];
  __syncthreads();

  const unsigned short* qTb = qT + (size_t)b * NQ * ND;
  const unsigned short* qSb = qSwz + (size_t)b * ND * NQ;
  const unsigned short* iSb = iSwz + (size_t)b * ND * NQ;
  f32x4 accA[2][2] = {};
  f32x4 accB[2][2] = {};

  for (int jc = 0; jc < 4; ++jc) {
    int j0 = jc * 64;
    f32x4 sA[2] = {};
    #pragma unroll
    for (int ks = 0; ks < 4; ++ks) {
      int g = ks * 4 + h;
      int off = ((g & 8) | ((g & 7) ^ (lr & 7))) * 8;
      bf16x8 bv = *(const bf16x8*)&qTb[(size_t)(j0 + w * 16 + lr) * ND + off];
      #pragma unroll
      for (int mi = 0; mi < 2; ++mi) {
        bf16x8 av = *(const bf16x8*)&cwA[(mi * 16 + lr) * 128 + off];
        sA[mi] = __builtin_amdgcn_mfma_f32_16x16x32_bf16(av, bv, sA[mi], 0, 0, 0);
      }
    }
    #pragma unroll
    for (int mi = 0; mi < 2; ++mi)
      #pragma unroll
      for (int r = 0; r < 4; ++r) {
        int i_ = mi * 16 + h * 4 + r;
        int j_ = w * 16 + lr;
        float sfull = sA[mi][r] + cbI[i_] + qbL[j0 + j_];
        float qm = qmL[j0 + j_];
        float vq = sfull * qm + NEGV * (1.f - qm);
        float p = __expf(vq - rmL[i_]) * riL[i_];
        Pl[i_ * 72 + (((j_ >> 3) ^ (i_ & 7)) << 3) + (j_ & 7)] = f2bf(p);
      }
    __syncthreads();
    #pragma unroll
    for (int ks = 0; ks < 2; ++ks) {
      bf16x8 aP[2], bQ[2], bI[2];
      #pragma unroll
      for (int mi = 0; mi < 2; ++mi) {
        int i = mi * 16 + lr;
        int slot = (ks * 4 + h) ^ (i & 7);
        aP[mi] = *(const bf16x8*)&Pl[i * 72 + slot * 8];
      }
      #pragma unroll
      for (int nd = 0; nd < 2; ++nd) {
        int d = w * 32 + nd * 16 + lr;
        int slot = (ks * 4 + h) ^ (d & 7);
        bQ[nd] = *(const bf16x8*)&qSb[(size_t)d * NQ + j0 + slot * 8];
        bI[nd] = *(const bf16x8*)&iSb[(size_t)d * NQ + j0 + slot * 8];
      }
      #pragma unroll
      for (int mi = 0; mi < 2; ++mi)
        #pragma unroll
        for (int nd = 0; nd < 2; ++nd) {
          accA[mi][nd] = __builtin_amdgcn_mfma_f32_16x16x32_bf16(aP[mi], bQ[nd], accA[mi][nd], 0, 0, 0);
          accB[mi][nd] = __builtin_amdgcn_mfma_f32_16x16x32_bf16(aP[mi], bI[nd], accB[mi][nd], 0, 0, 0);
        }
    }
    __syncthreads();
  }
  // epilogue (aliases cwA/Pl region)
  #pragma unroll
  for (int mi = 0; mi < 2; ++mi)
    #pragma unroll
    for (int nd = 0; nd < 2; ++nd) {
      int d = w * 32 + nd * 16 + lr;
      #pragma unroll
      for (int r = 0; r < 4; ++r) {
        int i = mi * 16 + h * 4 + r;
        As[i * 133 + d] = accA[mi][nd][r];
        Bs[i * 133 + d] = accB[mi][nd][r];
      }
    }
  __syncthreads();
  {
    int i4 = (t & 7) * 4, db = t >> 3;
    const float* Cb = C + (size_t)b * ND * NC;
    unsigned short* xb = xB + (size_t)b * 4 * ND * NC;
    #pragma unroll
    for (int p = 0; p < 4; ++p) {
      int d = db + p * 32;
      float4 c4 = *(const float4*)&Cb[(size_t)d * NC + i0 + i4];
      float4 a4, b4;
      a4.x = As[(i4 + 0) * 133 + d]; a4.y = As[(i4 + 1) * 133 + d];
      a4.z = As[(i4 + 2) * 133 + d]; a4.w = As[(i4 + 3) * 133 + d];
      b4.x = Bs[(i4 + 0) * 133 + d]; b4.y = Bs[(i4 + 1) * 133 + d];
      b4.z = Bs[(i4 + 2) * 133 + d]; b4.w = Bs[(i4 + 3) * 133 + d];
      u16x4 o0, o1, o2, o3;
      o0[0] = f2bf(c4.x); o0[1] = f2bf(c4.y); o0[2] = f2bf(c4.z); o0[3] = f2bf(c4.w);
      o1[0] = f2bf(a4.x); o1[1] = f2bf(a4.y); o1[2] = f2bf(a4.z); o1[3] = f2bf(a4.w);
      o2[0] = f2bf(c4.x * a4.x); o2[1] = f2bf(c4.y * a4.y); o2[2] = f2bf(c4.z * a4.z); o2[3] = f2bf(c4.w * a4.w);
      o3[0] = f2bf(c4.x * b4.x); o3[1] = f2bf(c4.y * b4.y); o3[2] = f2bf(c4.z * b4.z); o3[3] = f2bf(c4.w * b4.w);
      *(u16x4*)&xb[(size_t)(0 * ND + d) * NC + i0 + i4] = o0;
      *(u16x4*)&xb[(size_t)(1 * ND + d) * NC + i0 + i4] = o1;
      *(u16x4*)&xb[(size_t)(2 * ND + d) * NC + i0 + i4] = o2;
      *(u16x4*)&xb[(size_t)(3 * ND + d) * NC + i0 + i4] = o3;
    }
  }
}

// ---------------- K6 (MFMA): depthwise(k=5,pad2) + pointwise GEMM (R9 proven version)
__global__ __launch_bounds__(256) void k6_mfma(const unsigned short* __restrict__ x,
                                               const float* __restrict__ dwW, const float* __restrict__ dwB,
                                               const unsigned short* __restrict__ pwB16,
                                               const float* __restrict__ pwB, float* __restrict__ out) {
  extern __shared__ char sm6[];
  unsigned short* xs = (unsigned short*)sm6;            // [64][56]
  unsigned short* x1s = (unsigned short*)(sm6 + 7168);  // [32][72]
  unsigned short* pws = (unsigned short*)(sm6 + 11776); // [128][72]
  int b = blockIdx.y, l0 = blockIdx.x * 32;
  int t = threadIdx.x, w = t >> 6, l = t & 63, h = l >> 4, lr = l & 15;
  const unsigned short* xb = x + (size_t)b * 4 * ND * NC;
  f32x4 acc[2][2] = {};
  int cgw = t & 63, lb = w * 8;

  for (int ch = 0; ch < 8; ++ch) {
    int cg0 = ch * 64;
    __syncthreads();
    #pragma unroll
    for (int k = 0; k < 2; ++k) {
      int id2 = t + k * 256;
      if (id2 < 384) {
        int row = id2 / 6, seg = id2 % 6;
        int gl = l0 - 8 + seg * 8;
        u16x8 v = {};
        if ((unsigned)gl <= 1016u)
          v = *(const u16x8*)(xb + (size_t)(cg0 + row) * NC + gl);
        *(u16x8*)&xs[row * 56 + seg * 8] = v;
      }
    }
    #pragma unroll
    for (int k = 0; k < 4; ++k) {
      int id2 = t + k * 256;
      int o = id2 >> 3, s8 = id2 & 7;
      *(u16x8*)&pws[o * 72 + s8 * 8] = *(const u16x8*)(pwB16 + (size_t)o * 512 + cg0 + s8 * 8);
    }
    __syncthreads();
    {
      int gch = cg0 + cgw;
      float bias = dwB[gch];
      float dwv[5];
      #pragma unroll
      for (int tp = 0; tp < 5; ++tp) dwv[tp] = dwW[gch * 5 + tp];
      float f[24];
      #pragma unroll
      for (int s = 0; s < 3; ++s) {
        u16x8 v = *(const u16x8*)&xs[cgw * 56 + lb + s * 8];
        #pragma unroll
        for (int e = 0; e < 8; ++e) f[s * 8 + e] = bf2f(v[e]);
      }
      #pragma unroll
      for (int e = 0; e < 8; ++e) {
        float a = bias;
        #pragma unroll
        for (int tp = 0; tp < 5; ++tp)
          a = fmaf(f[e + 6 + tp], dwv[tp], a);
        x1s[(lb + e) * 72 + cgw] = f2bf(a);
      }
    }
    __syncthreads();
    #pragma unroll
    for (int ks = 0; ks < 2; ++ks) {
      bf16x8 aW[2], bX[2];
      #pragma unroll
      for (int mi = 0; mi < 2; ++mi) {
        int o = w * 32 + mi * 16 + lr;
        aW[mi] = *(const bf16x8*)&pws[o * 72 + ks * 32 + h * 8];
      }
      #pragma unroll
      for (int nf = 0; nf < 2; ++nf) {
        int ll = nf * 16 + lr;
        bX[nf] = *(const bf16x8*)&x1s[ll * 72 + ks * 32 + h * 8];
      }
      #pragma unroll
      for (int mi = 0; mi < 2; ++mi)
        #pragma unroll
        for (int nf = 0; nf < 2; ++nf)
          acc[mi][nf] = __builtin_amdgcn_mfma_f32_16x16x32_bf16(aW[mi], bX[nf], acc[mi][nf], 0, 0, 0);
    }
  }
  #pragma unroll
  for (int mi = 0; mi < 2; ++mi) {
    #pragma unroll
    for (int r = 0; r < 4; ++r) {
      int o = w * 32 + mi * 16 + h * 4 + r;
      float bv = pwB[o];
      #pragma unroll
      for (int nf = 0; nf < 2; ++nf)
        out[((size_t)b * ND + o) * NC + l0 + nf * 16 + lr] = acc[mi][nf][r] + bv;
    }
  }
}

extern "C" void kernel_launch(void* const* d_in, const int* in_sizes, int n_in,
                              void* d_out, int out_size, void* d_ws, size_t ws_size,
                              hipStream_t stream) {
  const float* C = (const float*)d_in[0];
  const float* Q = (const float*)d_in[1];
  const float* c_mask = (const float*)d_in[2];
  const float* q_mask = (const float*)d_in[3];
  const float* W0 = (const float*)d_in[4];
  const float* dwW = (const float*)d_in[5];
  const float* dwB = (const float*)d_in[6];
  const float* pwW = (const float*)d_in[7];
  const float* pwB = (const float*)d_in[8];
  float* out = (float*)d_out;
  float* ws = (float*)d_ws;

  float* rowmax = ws;                                  // NB*NC
  float* rowsum = rowmax + NB * NC;
  float* colmax = rowsum + NB * NC;                    // (unused, layout keep)
  float* colsum = colmax + NB * NQ;
  float* cb = colsum + NB * NQ;                        // NB*NC
  float* qb = cb + NB * NC;                            // NB*NQ
  float* colPm = qb + NB * NQ;                         // 16*NB*NQ
  float* colPs = colPm + 16 * NB * NQ;                 // 16*NB*NQ
  unsigned short* qSwz = (unsigned short*)(colPs + 16 * NB * NQ);   // NB*ND*NQ
  unsigned short* qT = qSwz + (size_t)NB * ND * NQ;                 // NB*NQ*ND
  unsigned short* iSwz = qT + (size_t)NB * NQ * ND;                 // NB*ND*NQ
  unsigned short* cw3T = iSwz + (size_t)NB * ND * NQ;               // NB*NC*ND
  unsigned short* cSwz = cw3T + (size_t)NB * NC * ND;               // NB*ND*NC
  unsigned short* pwB16 = cSwz + (size_t)NB * ND * NC;              // 128*512
  float* partial = (float*)(pwB16 + ND * 512);                      // 2*NB*ND*NQ f32
  unsigned short* xB = (unsigned short*)(partial + 2 * (size_t)NB * ND * NQ);  // NB*4*ND*NC

  k_prep<<<dim3(672), 256, 0, stream>>>(C, Q, pwW, W0, cw3T, cSwz, cb, qSwz, qT, qb, pwB16);
  k_stats<<<dim3(16, NB), 256, 0, stream>>>(cw3T, qT, cb, qb, q_mask, c_mask, rowmax, rowsum, colPm, colPs);
  k4f<<<dim3(16, NB), 256, 0, stream>>>(cw3T, qT, cSwz, cb, qb, c_mask, colPm, colPs, partial);
  k4c2<<<dim3(NB * ND * NQ / 4 / 256), 256, 0, stream>>>(partial, iSwz);
  k5f<<<dim3(NC / 32, NB), 256, 34048, stream>>>(cw3T, qT, qSwz, iSwz, C, cb, qb, q_mask, rowmax, rowsum, xB);
  k6_mfma<<<dim3(NC / 32, NB), 256, 30208, stream>>>(xB, dwW, dwB, pwB16, pwB, out);
}